// Round 1
// baseline (780.297 us; speedup 1.0000x reference)
//
#include <hip/hip_runtime.h>

#define BB 4
#define CC 84
#define CM 80
#define HH 512
#define WW 512
#define HWSZ (HH * WW)

// Pass A: probs[b,h,w] = max over channels 0..79 of points[b,c,h,w]
__global__ __launch_bounds__(256) void probs_kernel(const float* __restrict__ pts,
                                                    float* __restrict__ probs) {
    int tid = blockIdx.x * blockDim.x + threadIdx.x;   // 0 .. 262143
    int pix = tid << 2;                                // 4 pixels per thread
    int b   = pix >> 18;                               // / (512*512)
    int off = pix & (HWSZ - 1);
    const float4* base = (const float4*)(pts + (size_t)b * CC * HWSZ + off);
    float4 m = base[0];
#pragma unroll 4
    for (int c = 1; c < CM; ++c) {
        float4 v = base[c * (HWSZ / 4)];
        m.x = fmaxf(m.x, v.x);
        m.y = fmaxf(m.y, v.y);
        m.z = fmaxf(m.z, v.z);
        m.w = fmaxf(m.w, v.w);
    }
    ((float4*)probs)[tid] = m;
}

// Pass B: 3x3 NMS mask from probs (zero padding), then out = points * mask
// Reference semantics: neighbors with raster idx < 4 (above row + left) use
// strict >, idx > 4 (right + below row) use >=.
__global__ __launch_bounds__(256) void nms_mul_kernel(const float* __restrict__ pts,
                                                      const float* __restrict__ probs,
                                                      float* __restrict__ out) {
    int tid = blockIdx.x * blockDim.x + threadIdx.x;   // 0 .. 262143
    int pix = tid << 2;
    int b   = pix >> 18;
    int off = pix & (HWSZ - 1);
    int h   = off >> 9;          // / 512
    int w0  = off & (WW - 1);    // first of 4 consecutive w

    const float* pb = probs + b * HWSZ;

    // 3 rows x 6 cols neighborhood covering pixels w0..w0+3 with halo 1
    float rows[3][6];
#pragma unroll
    for (int r = 0; r < 3; ++r) {
        int hh = h + r - 1;
        bool hv = (hh >= 0) & (hh < HH);
        const float* rp = pb + hh * WW;
#pragma unroll
        for (int ci = 0; ci < 6; ++ci) {
            int ww = w0 + ci - 1;
            bool wv = (ww >= 0) & (ww < WW);
            rows[r][ci] = (hv & wv) ? rp[ww] : 0.0f;
        }
    }

    float fm[4];
    bool any = false;
#pragma unroll
    for (int j = 0; j < 4; ++j) {
        float v = rows[1][j + 1];
        bool m = (v >  rows[0][j]) & (v >  rows[0][j + 1]) & (v >  rows[0][j + 2])
               & (v >  rows[1][j]) & (v >= rows[1][j + 2])
               & (v >= rows[2][j]) & (v >= rows[2][j + 1]) & (v >= rows[2][j + 2]);
        fm[j] = m ? 1.0f : 0.0f;
        any |= m;
    }

    size_t bo = (size_t)b * CC * HWSZ + off;
    const float4* src = (const float4*)(pts + bo);
    float4* dst = (float4*)(out + bo);

    if (any) {
#pragma unroll 4
        for (int c = 0; c < CC; ++c) {
            float4 v = src[c * (HWSZ / 4)];
            float4 o;
            o.x = v.x * fm[0];
            o.y = v.y * fm[1];
            o.z = v.z * fm[2];
            o.w = v.w * fm[3];
            dst[c * (HWSZ / 4)] = o;
        }
    } else {
        float4 z = make_float4(0.f, 0.f, 0.f, 0.f);
#pragma unroll 4
        for (int c = 0; c < CC; ++c) {
            dst[c * (HWSZ / 4)] = z;
        }
    }
}

extern "C" void kernel_launch(void* const* d_in, const int* in_sizes, int n_in,
                              void* d_out, int out_size, void* d_ws, size_t ws_size,
                              hipStream_t stream) {
    const float* pts = (const float*)d_in[0];
    float* out   = (float*)d_out;
    float* probs = (float*)d_ws;   // 4*512*512*4 = 4 MiB scratch

    int nthreads = (BB * HWSZ) / 4;   // 262144
    dim3 blk(256);
    dim3 grd(nthreads / 256);         // 1024 blocks

    probs_kernel<<<grd, blk, 0, stream>>>(pts, probs);
    nms_mul_kernel<<<grd, blk, 0, stream>>>(pts, probs, out);
}

// Round 2
// 624.447 us; speedup vs baseline: 1.2496x; 1.2496x over previous
//
#include <hip/hip_runtime.h>

#define BB 4
#define CC 84
#define CM 80
#define HH 512
#define WW 512
#define HWSZ (HH * WW)
#define PG (HWSZ / 4)          // 65536 float4 pixel-groups per image

// ---------------- Pass A: partial channel-max ----------------
// partial layout: [(chunk*BB + b)*PG + pg] as float4  (chunk-major),
// so chunk 0 region == final probs layout [b*PG + pg].
template <int NCH>
__global__ __launch_bounds__(256) void partial_max_kernel(const float* __restrict__ pts,
                                                          float* __restrict__ partial) {
    constexpr int CPC = CM / NCH;                  // channels per chunk
    int tid = blockIdx.x * blockDim.x + threadIdx.x;   // BB*NCH*PG threads
    int pg  = tid & (PG - 1);
    int r   = tid >> 16;
    int chunk = (NCH == 1) ? 0 : (r % NCH);
    int b     = (NCH == 1) ? r : (r / NCH);

    const float4* base = (const float4*)pts + ((size_t)b * CC + chunk * CPC) * PG + pg;
    float4 m = base[0];
#pragma unroll 8
    for (int c = 1; c < CPC; ++c) {
        float4 v = base[(size_t)c * PG];
        m.x = fmaxf(m.x, v.x);
        m.y = fmaxf(m.y, v.y);
        m.z = fmaxf(m.z, v.z);
        m.w = fmaxf(m.w, v.w);
    }
    ((float4*)partial)[((size_t)chunk * BB + b) * PG + pg] = m;
}

// ---------------- combine partials -> probs (in-place into chunk 0) ----------
template <int NCH>
__global__ __launch_bounds__(256) void combine_kernel(float* __restrict__ partial) {
    int tid = blockIdx.x * blockDim.x + threadIdx.x;   // BB*PG threads
    int pg  = tid & (PG - 1);
    int b   = tid >> 16;
    float4* p = (float4*)partial;
    float4 m = p[(size_t)b * PG + pg];                 // chunk 0
#pragma unroll
    for (int ch = 1; ch < NCH; ++ch) {
        float4 v = p[((size_t)ch * BB + b) * PG + pg];
        m.x = fmaxf(m.x, v.x);
        m.y = fmaxf(m.y, v.y);
        m.z = fmaxf(m.z, v.z);
        m.w = fmaxf(m.w, v.w);
    }
    p[(size_t)b * PG + pg] = m;                        // becomes probs
}

// ---------------- mask from probs (3x3 NMS, zero pad) ----------------
// Reference: raster idx < center uses strict >, idx > center uses >=.
__global__ __launch_bounds__(256) void mask_kernel(const float* __restrict__ probs,
                                                   float* __restrict__ mask) {
    int tid = blockIdx.x * blockDim.x + threadIdx.x;   // BB*PG threads
    int pg  = tid & (PG - 1);
    int b   = tid >> 16;
    int off = pg << 2;
    int h   = off >> 9;
    int w0  = off & (WW - 1);

    const float* pb = probs + (size_t)b * HWSZ;

    float rows[3][6];
#pragma unroll
    for (int r = 0; r < 3; ++r) {
        int hh = h + r - 1;
        bool hv = (hh >= 0) & (hh < HH);
        const float* rp = pb + hh * WW;
#pragma unroll
        for (int ci = 0; ci < 6; ++ci) {
            int ww = w0 + ci - 1;
            bool wv = (ww >= 0) & (ww < WW);
            rows[r][ci] = (hv & wv) ? rp[ww] : 0.0f;
        }
    }

    float4 fm;
    float* fmp = &fm.x;
#pragma unroll
    for (int j = 0; j < 4; ++j) {
        float v = rows[1][j + 1];
        bool m = (v >  rows[0][j]) & (v >  rows[0][j + 1]) & (v >  rows[0][j + 2])
               & (v >  rows[1][j]) & (v >= rows[1][j + 2])
               & (v >= rows[2][j]) & (v >= rows[2][j + 1]) & (v >= rows[2][j + 2]);
        fmp[j] = m ? 1.0f : 0.0f;
    }
    ((float4*)mask)[(size_t)b * PG + pg] = fm;
}

// ---------------- multiply: out = points * mask ----------------
__global__ __launch_bounds__(256) void mul_kernel(const float* __restrict__ pts,
                                                  const float* __restrict__ mask,
                                                  float* __restrict__ out) {
    int tid = blockIdx.x * blockDim.x + threadIdx.x;   // BB*CC*PG threads
    int pg  = tid & (PG - 1);
    int r   = tid >> 16;                               // [0, BB*CC)
    int c   = r % CC;
    int b   = r / CC;

    float4 m = ((const float4*)mask)[(size_t)b * PG + pg];
    size_t idx = ((size_t)b * CC + c) * PG + pg;

    int nz = (__float_as_uint(m.x) | __float_as_uint(m.y) |
              __float_as_uint(m.z) | __float_as_uint(m.w));
    if (nz) {
        float4 v = ((const float4*)pts)[idx];
        float4 o;
        o.x = v.x * m.x;
        o.y = v.y * m.y;
        o.z = v.z * m.z;
        o.w = v.w * m.w;
        ((float4*)out)[idx] = o;
    } else {
        ((float4*)out)[idx] = make_float4(0.f, 0.f, 0.f, 0.f);
    }
}

// ---------------- round-1 fallback (ws < 8 MiB) ----------------
__global__ __launch_bounds__(256) void probs_kernel_fb(const float* __restrict__ pts,
                                                       float* __restrict__ probs) {
    int tid = blockIdx.x * blockDim.x + threadIdx.x;
    int pix = tid << 2;
    int b   = pix >> 18;
    int off = pix & (HWSZ - 1);
    const float4* base = (const float4*)(pts + (size_t)b * CC * HWSZ + off);
    float4 m = base[0];
#pragma unroll 4
    for (int c = 1; c < CM; ++c) {
        float4 v = base[c * (HWSZ / 4)];
        m.x = fmaxf(m.x, v.x); m.y = fmaxf(m.y, v.y);
        m.z = fmaxf(m.z, v.z); m.w = fmaxf(m.w, v.w);
    }
    ((float4*)probs)[tid] = m;
}

__global__ __launch_bounds__(256) void nms_mul_kernel_fb(const float* __restrict__ pts,
                                                         const float* __restrict__ probs,
                                                         float* __restrict__ out) {
    int tid = blockIdx.x * blockDim.x + threadIdx.x;
    int pix = tid << 2;
    int b   = pix >> 18;
    int off = pix & (HWSZ - 1);
    int h   = off >> 9;
    int w0  = off & (WW - 1);
    const float* pb = probs + b * HWSZ;
    float rows[3][6];
#pragma unroll
    for (int r = 0; r < 3; ++r) {
        int hh = h + r - 1;
        bool hv = (hh >= 0) & (hh < HH);
        const float* rp = pb + hh * WW;
#pragma unroll
        for (int ci = 0; ci < 6; ++ci) {
            int ww = w0 + ci - 1;
            bool wv = (ww >= 0) & (ww < WW);
            rows[r][ci] = (hv & wv) ? rp[ww] : 0.0f;
        }
    }
    float fm[4];
    bool any = false;
#pragma unroll
    for (int j = 0; j < 4; ++j) {
        float v = rows[1][j + 1];
        bool m = (v >  rows[0][j]) & (v >  rows[0][j + 1]) & (v >  rows[0][j + 2])
               & (v >  rows[1][j]) & (v >= rows[1][j + 2])
               & (v >= rows[2][j]) & (v >= rows[2][j + 1]) & (v >= rows[2][j + 2]);
        fm[j] = m ? 1.0f : 0.0f;
        any |= m;
    }
    size_t bo = (size_t)b * CC * HWSZ + off;
    const float4* src = (const float4*)(pts + bo);
    float4* dst = (float4*)(out + bo);
    if (any) {
#pragma unroll 4
        for (int c = 0; c < CC; ++c) {
            float4 v = src[c * (HWSZ / 4)];
            float4 o;
            o.x = v.x * fm[0]; o.y = v.y * fm[1];
            o.z = v.z * fm[2]; o.w = v.w * fm[3];
            dst[c * (HWSZ / 4)] = o;
        }
    } else {
        float4 z = make_float4(0.f, 0.f, 0.f, 0.f);
#pragma unroll 4
        for (int c = 0; c < CC; ++c) dst[c * (HWSZ / 4)] = z;
    }
}

extern "C" void kernel_launch(void* const* d_in, const int* in_sizes, int n_in,
                              void* d_out, int out_size, void* d_ws, size_t ws_size,
                              hipStream_t stream) {
    const float* pts = (const float*)d_in[0];
    float* out = (float*)d_out;
    float* ws  = (float*)d_ws;

    const size_t MB4 = (size_t)BB * HWSZ * sizeof(float);   // 4 MiB plane
    dim3 blk(256);
    int npg_threads = BB * PG;                              // 262144
    dim3 grd_pg(npg_threads / 256);                         // 1024

    if (ws_size >= 5 * MB4) {                               // NCH=4 path: 20 MiB
        constexpr int NCH = 4;
        float* partial = ws;                                 // 16 MiB
        float* probs   = ws;                                 // alias chunk 0
        float* mask    = ws + NCH * (size_t)BB * HWSZ;       // at 16 MiB
        partial_max_kernel<NCH><<<dim3(BB * NCH * PG / 256), blk, 0, stream>>>(pts, partial);
        combine_kernel<NCH><<<grd_pg, blk, 0, stream>>>(partial);
        mask_kernel<<<grd_pg, blk, 0, stream>>>(probs, mask);
        mul_kernel<<<dim3(BB * CC * PG / 256), blk, 0, stream>>>(pts, mask, out);
    } else if (ws_size >= 3 * MB4) {                        // NCH=2 path: 12 MiB
        constexpr int NCH = 2;
        float* partial = ws;
        float* probs   = ws;
        float* mask    = ws + NCH * (size_t)BB * HWSZ;
        partial_max_kernel<NCH><<<dim3(BB * NCH * PG / 256), blk, 0, stream>>>(pts, partial);
        combine_kernel<NCH><<<grd_pg, blk, 0, stream>>>(partial);
        mask_kernel<<<grd_pg, blk, 0, stream>>>(probs, mask);
        mul_kernel<<<dim3(BB * CC * PG / 256), blk, 0, stream>>>(pts, mask, out);
    } else if (ws_size >= 2 * MB4) {                        // NCH=1 path: 8 MiB
        float* probs = ws;
        float* mask  = ws + (size_t)BB * HWSZ;
        partial_max_kernel<1><<<grd_pg, blk, 0, stream>>>(pts, probs);
        mask_kernel<<<grd_pg, blk, 0, stream>>>(probs, mask);
        mul_kernel<<<dim3(BB * CC * PG / 256), blk, 0, stream>>>(pts, mask, out);
    } else {                                                // round-1 fallback: 4 MiB
        float* probs = ws;
        probs_kernel_fb<<<grd_pg, blk, 0, stream>>>(pts, probs);
        nms_mul_kernel_fb<<<grd_pg, blk, 0, stream>>>(pts, probs, out);
    }
}

// Round 3
// 613.820 us; speedup vs baseline: 1.2712x; 1.0173x over previous
//
#include <hip/hip_runtime.h>

#define BB 4
#define CC 84
#define CM 80
#define HH 512
#define WW 512
#define HWSZ (HH * WW)
#define PG (HWSZ / 4)          // 65536 float4 pixel-groups per image
#define NCH 4
#define CPC (CM / NCH)         // 20 channels per chunk

typedef float v4f __attribute__((ext_vector_type(4)));

static __device__ __forceinline__ v4f vmax4(v4f a, v4f b) {
    v4f r;
    r.x = fmaxf(a.x, b.x);
    r.y = fmaxf(a.y, b.y);
    r.z = fmaxf(a.z, b.z);
    r.w = fmaxf(a.w, b.w);
    return r;
}

// ---------------- K1: partial channel-max (NCH chunks of 20 channels) -------
// partial layout: [(chunk*BB + b)*PG + pg] float4
__global__ __launch_bounds__(256) void partial_max_kernel(const float* __restrict__ pts,
                                                          float* __restrict__ partial) {
    int tid = blockIdx.x * blockDim.x + threadIdx.x;   // BB*NCH*PG threads
    int pg  = tid & (PG - 1);
    int r   = tid >> 16;
    int chunk = r % NCH;
    int b     = r / NCH;

    const v4f* base = (const v4f*)pts + ((size_t)b * CC + chunk * CPC) * PG + pg;
    v4f m = __builtin_nontemporal_load(base);
#pragma unroll 5
    for (int c = 1; c < CPC; ++c) {
        v4f v = __builtin_nontemporal_load(base + (size_t)c * PG);
        m = vmax4(m, v);
    }
    ((v4f*)partial)[((size_t)chunk * BB + b) * PG + pg] = m;
}

// ---------------- K2: fused combine + 3x3 NMS mask --------------------------
// probs(b,h,w) = max over 4 partial planes; mask per reference:
// raster idx < center uses strict >, idx > center uses >=; zero padding.
__global__ __launch_bounds__(256) void fused_mask_kernel(const float* __restrict__ partial,
                                                         float* __restrict__ mask) {
    int tid = blockIdx.x * blockDim.x + threadIdx.x;   // BB*PG threads
    int pg  = tid & (PG - 1);
    int b   = tid >> 16;
    int off = pg << 2;
    int h   = off >> 9;
    int w0  = off & (WW - 1);

    float rows[3][6];
#pragma unroll
    for (int r = 0; r < 3; ++r) {
        int hh = h + r - 1;
        bool hv = (hh >= 0) & (hh < HH);
#pragma unroll
        for (int ci = 0; ci < 6; ++ci) {
            int ww = w0 + ci - 1;
            bool wv = (ww >= 0) & (ww < WW);
            float v = 0.0f;
            if (hv & wv) {
                int pidx = hh * WW + ww;
                v = partial[(size_t)(0 * BB + b) * HWSZ + pidx];
#pragma unroll
                for (int ch = 1; ch < NCH; ++ch)
                    v = fmaxf(v, partial[(size_t)(ch * BB + b) * HWSZ + pidx]);
            }
            rows[r][ci] = v;
        }
    }

    v4f fm;
#pragma unroll
    for (int j = 0; j < 4; ++j) {
        float v = rows[1][j + 1];
        bool m = (v >  rows[0][j]) & (v >  rows[0][j + 1]) & (v >  rows[0][j + 2])
               & (v >  rows[1][j]) & (v >= rows[1][j + 2])
               & (v >= rows[2][j]) & (v >= rows[2][j + 1]) & (v >= rows[2][j + 2]);
        float f = m ? 1.0f : 0.0f;
        if (j == 0) fm.x = f;
        else if (j == 1) fm.y = f;
        else if (j == 2) fm.z = f;
        else fm.w = f;
    }
    ((v4f*)mask)[(size_t)b * PG + pg] = fm;
}

// ---------------- K3: out = points * mask -----------------------------------
// Block order: 84 consecutive blocks share one 4 KiB mask chunk (L2 reuse).
__global__ __launch_bounds__(256) void mul_kernel(const float* __restrict__ pts,
                                                  const float* __restrict__ mask,
                                                  float* __restrict__ out) {
    int gid = blockIdx.x;            // BB * CC * (PG/256) = 86016
    int c   = gid % CC;
    int pc  = gid / CC;              // 0..1023
    int b   = pc >> 8;
    int pg  = ((pc & 255) << 8) + threadIdx.x;

    v4f m = ((const v4f*)mask)[(size_t)b * PG + pg];
    size_t idx = ((size_t)b * CC + c) * PG + pg;

    unsigned nz = (__float_as_uint(m.x) | __float_as_uint(m.y) |
                   __float_as_uint(m.z) | __float_as_uint(m.w));
    v4f o;
    if (nz) {
        v4f v = __builtin_nontemporal_load((const v4f*)pts + idx);
        o.x = v.x * m.x;
        o.y = v.y * m.y;
        o.z = v.z * m.z;
        o.w = v.w * m.w;
    } else {
        o.x = 0.f; o.y = 0.f; o.z = 0.f; o.w = 0.f;
    }
    __builtin_nontemporal_store(o, (v4f*)out + idx);
}

// ---------------- fallback (ws too small): round-1 two-kernel path ----------
__global__ __launch_bounds__(256) void probs_kernel_fb(const float* __restrict__ pts,
                                                       float* __restrict__ probs) {
    int tid = blockIdx.x * blockDim.x + threadIdx.x;
    int pix = tid << 2;
    int b   = pix >> 18;
    int off = pix & (HWSZ - 1);
    const float4* base = (const float4*)(pts + (size_t)b * CC * HWSZ + off);
    float4 m = base[0];
#pragma unroll 4
    for (int c = 1; c < CM; ++c) {
        float4 v = base[c * (HWSZ / 4)];
        m.x = fmaxf(m.x, v.x); m.y = fmaxf(m.y, v.y);
        m.z = fmaxf(m.z, v.z); m.w = fmaxf(m.w, v.w);
    }
    ((float4*)probs)[tid] = m;
}

__global__ __launch_bounds__(256) void nms_mul_kernel_fb(const float* __restrict__ pts,
                                                         const float* __restrict__ probs,
                                                         float* __restrict__ out) {
    int tid = blockIdx.x * blockDim.x + threadIdx.x;
    int pix = tid << 2;
    int b   = pix >> 18;
    int off = pix & (HWSZ - 1);
    int h   = off >> 9;
    int w0  = off & (WW - 1);
    const float* pb = probs + b * HWSZ;
    float rows[3][6];
#pragma unroll
    for (int r = 0; r < 3; ++r) {
        int hh = h + r - 1;
        bool hv = (hh >= 0) & (hh < HH);
        const float* rp = pb + hh * WW;
#pragma unroll
        for (int ci = 0; ci < 6; ++ci) {
            int ww = w0 + ci - 1;
            bool wv = (ww >= 0) & (ww < WW);
            rows[r][ci] = (hv & wv) ? rp[ww] : 0.0f;
        }
    }
    float fm[4];
    bool any = false;
#pragma unroll
    for (int j = 0; j < 4; ++j) {
        float v = rows[1][j + 1];
        bool m = (v >  rows[0][j]) & (v >  rows[0][j + 1]) & (v >  rows[0][j + 2])
               & (v >  rows[1][j]) & (v >= rows[1][j + 2])
               & (v >= rows[2][j]) & (v >= rows[2][j + 1]) & (v >= rows[2][j + 2]);
        fm[j] = m ? 1.0f : 0.0f;
        any |= m;
    }
    size_t bo = (size_t)b * CC * HWSZ + off;
    const float4* src = (const float4*)(pts + bo);
    float4* dst = (float4*)(out + bo);
    if (any) {
#pragma unroll 4
        for (int c = 0; c < CC; ++c) {
            float4 v = src[c * (HWSZ / 4)];
            float4 o;
            o.x = v.x * fm[0]; o.y = v.y * fm[1];
            o.z = v.z * fm[2]; o.w = v.w * fm[3];
            dst[c * (HWSZ / 4)] = o;
        }
    } else {
        float4 z = make_float4(0.f, 0.f, 0.f, 0.f);
#pragma unroll 4
        for (int c = 0; c < CC; ++c) dst[c * (HWSZ / 4)] = z;
    }
}

extern "C" void kernel_launch(void* const* d_in, const int* in_sizes, int n_in,
                              void* d_out, int out_size, void* d_ws, size_t ws_size,
                              hipStream_t stream) {
    const float* pts = (const float*)d_in[0];
    float* out = (float*)d_out;
    float* ws  = (float*)d_ws;

    const size_t MB4 = (size_t)BB * HWSZ * sizeof(float);   // 4 MiB plane
    dim3 blk(256);
    dim3 grd_pg(BB * PG / 256);                              // 1024

    if (ws_size >= (NCH + 1) * MB4) {                        // 20 MiB needed
        float* partial = ws;                                 // 16 MiB
        float* mask    = ws + (size_t)NCH * BB * HWSZ;       // 4 MiB
        partial_max_kernel<<<dim3(BB * NCH * PG / 256), blk, 0, stream>>>(pts, partial);
        fused_mask_kernel<<<grd_pg, blk, 0, stream>>>(partial, mask);
        mul_kernel<<<dim3(BB * CC * (PG / 256)), blk, 0, stream>>>(pts, mask, out);
    } else {                                                 // 4 MiB fallback
        float* probs = ws;
        probs_kernel_fb<<<grd_pg, blk, 0, stream>>>(pts, probs);
        nms_mul_kernel_fb<<<grd_pg, blk, 0, stream>>>(pts, probs, out);
    }
}